// Round 18
// baseline (168.549 us; speedup 1.0000x reference)
//
#include <hip/hip_runtime.h>
#include <hip/hip_bf16.h>

#define DIM 256
#define HEADS 8
#define DHEAD 32
#define SEQ 2048
#define BATCH 2
#define NROWS (BATCH*SEQ)    // 4096 total rows
#define EPS 1e-5f

typedef __attribute__((ext_vector_type(8))) short bf16x8;   // MFMA A/B frag (4 VGPRs)
typedef __attribute__((ext_vector_type(4))) short bf16x4;   // 4 bf16 (8B)
typedef __attribute__((ext_vector_type(4))) float f32x4;    // MFMA C/D frag

__device__ __forceinline__ unsigned short f2b(float f) {
    __hip_bfloat16 h = __float2bfloat16(f);
    return *reinterpret_cast<unsigned short*>(&h);
}

// ---------------------------------------------------------------------------
// Kernel 1 (VERBATIM, passed): MFMA qkv projection; V written fragment-packed.
// ---------------------------------------------------------------------------
__global__ __launch_bounds__(1024) void qkv_mfma(
        const float* __restrict__ x,
        const unsigned short* __restrict__ WqP,
        const unsigned short* __restrict__ WkP,
        const unsigned short* __restrict__ WvP,
        unsigned short* __restrict__ qo,
        unsigned short* __restrict__ ko,
        unsigned short* __restrict__ VP) {
    __shared__ __align__(16) unsigned short xsb[16][264];

    const int t    = threadIdx.x;         // 0..1023
    const int w    = t >> 6;              // wave 0..15 = n-tile
    const int lane = t & 63;
    const int quad = lane >> 4;
    const int c16  = lane & 15;
    const int r0   = blockIdx.x * 16;
    const f32x4 zero = (f32x4){0.f, 0.f, 0.f, 0.f};

    // stage A: 16 rows x 256 cols fp32 -> bf16 LDS (1024 x float4)
    {
        const int row = t >> 6, c4 = (t & 63) * 4;
        float4 v4 = *(const float4*)&x[(size_t)(r0 + row) * 256 + c4];
        bf16x4 b4;
        b4[0] = (short)f2b(v4.x); b4[1] = (short)f2b(v4.y);
        b4[2] = (short)f2b(v4.z); b4[3] = (short)f2b(v4.w);
        *(bf16x4*)&xsb[row][c4] = b4;
    }

    f32x4 aq = zero, ak = zero, av = zero;
    const unsigned short* bq = WqP + (size_t)w * 4096 + (size_t)lane * 8;
    const unsigned short* bk = WkP + (size_t)w * 4096 + (size_t)lane * 8;
    const unsigned short* bv = WvP + (size_t)w * 4096 + (size_t)lane * 8;

    bf16x8 q0 = *(const bf16x8*)(bq);
    bf16x8 k0 = *(const bf16x8*)(bk);
    bf16x8 v0 = *(const bf16x8*)(bv);
    __syncthreads();   // xsb visible

#pragma unroll
    for (int ks = 0; ks < 8; ks++) {
        const int ksn = (ks + 1 < 8) ? ks + 1 : ks;     // last iter: dummy
        bf16x8 qn = *(const bf16x8*)(bq + ksn * 512);
        bf16x8 kn = *(const bf16x8*)(bk + ksn * 512);
        bf16x8 vn = *(const bf16x8*)(bv + ksn * 512);
        bf16x8 af = *(const bf16x8*)&xsb[c16][ks * 32 + quad * 8];
        aq = __builtin_amdgcn_mfma_f32_16x16x32_bf16(af, q0, aq, 0, 0, 0);
        ak = __builtin_amdgcn_mfma_f32_16x16x32_bf16(af, k0, ak, 0, 0, 0);
        av = __builtin_amdgcn_mfma_f32_16x16x32_bf16(af, v0, av, 0, 0, 0);
        q0 = qn; k0 = kn; v0 = vn;
    }

    // epilogue (C/D layout: row=quad*4+reg, col=w*16+c16)
    const float scale = 0.17677669529663687f;  // 1/sqrt(32)
    const int col = w * 16 + c16;
#pragma unroll
    for (int reg = 0; reg < 4; reg++) {
        const int row = r0 + quad * 4 + reg;
        qo[(size_t)row * 256 + col] = f2b(aq[reg] * scale);
        ko[(size_t)row * 256 + col] = f2b(ak[reg]);
    }
    {   // V fragment-packed
        const int bb   = r0 >> 11;
        const int key  = (r0 & 2047) + quad * 4;          // first of 4 keys
        const int jt   = key >> 6;
        const int kh   = (key >> 5) & 1;
        const int qv   = (key >> 3) & 3;
        const int j0   = key & 7;                          // 0 or 4
        const size_t off = ((((size_t)(bb * 32 + jt) * 32) + (w * 2 + kh)) * 64
                            + qv * 16 + c16) * 8 + j0;
        bf16x4 v4;
        v4[0] = (short)f2b(av[0]); v4[1] = (short)f2b(av[1]);
        v4[2] = (short)f2b(av[2]); v4[3] = (short)f2b(av[3]);
        *(bf16x4*)&VP[off] = v4;
    }
}

// ---------------------------------------------------------------------------
// Kernel 2 (SPLIT this round for observability): flash attention.
//  Identical math; fid = blockIdx.x + fid_base so the 512-block grid can be
//  launched as two 256-block halves (~27us each).  This lets any kernel
//  longer than ~28us surface in the rocprof top-5 (previously masked by
//  55us attn instances filling all 5 slots).
// ---------------------------------------------------------------------------
__global__ __launch_bounds__(256, 2) void attn_mfma(
        const unsigned short* __restrict__ qb,
        const unsigned short* __restrict__ kb,
        const unsigned short* __restrict__ VP,
        unsigned short* __restrict__ AP,
        int fid_base) {
    __shared__ __align__(16) unsigned short Ks[2][128][40];  // 20.5 KB
    __shared__ __align__(16) unsigned short Ps[2][64][132];  // 33.8 KB
    __shared__ float linv[64];

    const int t    = threadIdx.x;
    const int w    = t >> 6;
    const int lane = t & 63;
    const int quad = lane >> 4;
    const int c16  = lane & 15;

    const int fid  = blockIdx.x + fid_base;
    const int h    = fid & 7;
    const int b    = (fid >> 3) & 1;
    const int i0b  = (fid >> 4) * 64;        // block q-row base
    const int i0   = i0b + w * 16;           // this wave's q rows (QK phase)

    const size_t qk_head = ((size_t)b * SEQ) * DIM + h * DHEAD;
    const int ncol0 = w * 64;                // this wave's PV column slice

    bf16x8 qf = *(const bf16x8*)&qb[qk_head + (size_t)(i0 + c16) * DIM + quad * 8];

    const int kkey  = t >> 2, kpart = t & 3;   // 2 K-frags/thread (128 keys)
    const unsigned short* ksrc = kb + qk_head + (size_t)kkey * DIM + kpart * 8;

    f32x4 acc[4][4];
#pragma unroll
    for (int rt = 0; rt < 4; rt++)
#pragma unroll
        for (int ct = 0; ct < 4; ct++) acc[rt][ct] = (f32x4){0.f, 0.f, 0.f, 0.f};
    float lrow[4] = {0.f, 0.f, 0.f, 0.f};
    const f32x4 zero = (f32x4){0.f, 0.f, 0.f, 0.f};

    bf16x8 kregA = *(const bf16x8*)(ksrc);                      // keys kkey
    bf16x8 kregB = *(const bf16x8*)(ksrc + (size_t)64 * DIM);   // keys 64+kkey

    for (int jt = 0; jt < SEQ / 128; jt++) {
        const int cur = jt & 1;
        // commit K tile jt (prefetched) -> LDS buffer cur
        *(bf16x8*)&Ks[cur][kkey][kpart * 8]      = kregA;
        *(bf16x8*)&Ks[cur][64 + kkey][kpart * 8] = kregB;
        __syncthreads();   // (B) K tile jt visible

        // V fragments for this 128-key tile: 16 coalesced 1KB loads
        bf16x8 vreg[16];
#pragma unroll
        for (int hh = 0; hh < 2; hh++) {
            const unsigned short* vsrc = VP +
                (((size_t)(b * 32 + jt * 2 + hh) * 32) + w * 8) * 512 + (size_t)lane * 8;
#pragma unroll
            for (int ct = 0; ct < 4; ct++) {
                vreg[(hh * 2 + 0) * 4 + ct] = *(const bf16x8*)(vsrc + (ct * 2 + 0) * 512);
                vreg[(hh * 2 + 1) * 4 + ct] = *(const bf16x8*)(vsrc + (ct * 2 + 1) * 512);
            }
        }

        // K prefetch for jt+1 (retires under compute)
        if (jt + 1 < SEQ / 128) {
            const size_t j1 = (size_t)((jt + 1) * 128) * DIM;
            kregA = *(const bf16x8*)(ksrc + j1);
            kregB = *(const bf16x8*)(ksrc + j1 + (size_t)64 * DIM);
        }

        // ---- QK^T (M-split): this wave's 16 rows vs 128 keys, K from LDS
        f32x4 s[8];
#pragma unroll
        for (int kt = 0; kt < 8; kt++) {
            bf16x8 kf = *(const bf16x8*)&Ks[cur][kt * 16 + c16][quad * 8];
            s[kt] = __builtin_amdgcn_mfma_f32_16x16x32_bf16(qf, kf, zero, 0, 0, 0);
        }

        // ---- softmax (no max subtraction), stash P into buffer cur
#pragma unroll
        for (int kt = 0; kt < 8; kt++) {
#pragma unroll
            for (int reg = 0; reg < 4; reg++) {
                float p = __expf(s[kt][reg]);
                lrow[reg] += p;
                Ps[cur][w * 16 + quad * 4 + reg][kt * 16 + c16] = f2b(p);
            }
        }
        __syncthreads();   // (C) P visible to all waves

        // ---- PV (N-split): all 64 rows x this wave's 64 cols, V from regs
#pragma unroll
        for (int kh = 0; kh < 4; kh++) {
#pragma unroll
            for (int rt = 0; rt < 4; rt++) {
                bf16x8 af = *(const bf16x8*)&Ps[cur][rt * 16 + c16][kh * 32 + quad * 8];
#pragma unroll
                for (int ct = 0; ct < 4; ct++)
                    acc[rt][ct] = __builtin_amdgcn_mfma_f32_16x16x32_bf16(
                        af, vreg[kh * 4 + ct], acc[rt][ct], 0, 0, 0);
            }
        }
        // no (A) barrier: next iteration writes the other buffer
    }

    // ---- l broadcast: owner wave writes 1/l for its 16 rows
#pragma unroll
    for (int reg = 0; reg < 4; reg++) {
        float l = lrow[reg];
#pragma unroll
        for (int m = 1; m <= 8; m <<= 1) l += __shfl_xor(l, m, 64);
        if (c16 == 0) linv[w * 16 + quad * 4 + reg] = 1.f / l;
    }
    __syncthreads();

    // ---- write out fragment-packed (AP)
    const int R16base = (b * SEQ + i0b) >> 4;   // b*128 + i0b/16
#pragma unroll
    for (int rt = 0; rt < 4; rt++) {
#pragma unroll
        for (int reg = 0; reg < 4; reg++) {
            const float inv = linv[rt * 16 + quad * 4 + reg];
#pragma unroll
            for (int ct = 0; ct < 4; ct++) {
                const size_t frag = (size_t)(R16base + rt) * 64
                                  + h * 8 + w * 2 + (ct >> 1);
                const int l2 = ((ct * 2 + (c16 >> 3)) & 3) * 16 + quad * 4 + reg;
                AP[frag * 512 + l2 * 8 + (c16 & 7)] = f2b(acc[rt][ct][reg] * inv);
            }
        }
    }
}

// ---------------------------------------------------------------------------
// Kernel 3 (VERBATIM, passed): fragment-packed weights, coalesced reads.
// ---------------------------------------------------------------------------
__global__ void wprep(const float* __restrict__ Wo,
                      const float* __restrict__ Wf1,
                      const float* __restrict__ Wf2,
                      const float* __restrict__ Wq,
                      const float* __restrict__ Wk,
                      const float* __restrict__ Wv,
                      unsigned short* __restrict__ WoP,
                      unsigned short* __restrict__ W1P,
                      unsigned short* __restrict__ W2P,
                      unsigned short* __restrict__ WqP,
                      unsigned short* __restrict__ WkP,
                      unsigned short* __restrict__ WvP) {
    const int tid = blockIdx.x * 256 + threadIdx.x;
    const int stride = gridDim.x * 256;
    const int R1 = 65536;             // WoP rows
    const int R2 = R1 + 16384;        // W1P rows
    const int R3 = R2 + 16384;        // W2P rows
    const int R4 = R3 + 8192;         // WqP rows
    const int R5 = R4 + 8192;         // WkP rows
    const int R6 = R5 + 8192;         // WvP rows
    for (int r = tid; r < R6; r += stride) {
        const float* src;
        unsigned short* dst;
        int l, kbase, n, K;
        int ro;
        if (r < R1) {
            ro = r; l = ro & 63;
            int KS = (ro >> 6) & 63, NT = ro >> 12;
            n = NT * 16 + (l & 15); kbase = KS * 32 + ((l >> 4) << 3);
            src = Wo; dst = WoP; K = 256;
        } else if (r < R2) {
            ro = r - R1; l = ro & 63;
            int KS = (ro >> 6) & 7, NT = ro >> 9;
            n = NT * 16 + (l & 15); kbase = KS * 32 + ((l >> 4) << 3);
            src = Wf1; dst = W1P; K = 512;
        } else if (r < R3) {
            ro = r - R2; l = ro & 63;
            int KS = (ro >> 6) & 15, NT = ro >> 10;
            n = NT * 16 + (l & 15); kbase = KS * 32 + ((l >> 4) << 3);
            src = Wf2; dst = W2P; K = 256;
        } else {
            ro = (r - R3) & 8191; l = ro & 63;
            int KS = (ro >> 6) & 7, NT = ro >> 9;
            n = NT * 16 + (l & 15); kbase = KS * 32 + ((l >> 4) << 3);
            src = (r < R4) ? Wq : (r < R5) ? Wk : Wv;
            dst = (r < R4) ? WqP : (r < R5) ? WkP : WvP;
            K = 256;
        }
        bf16x8 o;
#pragma unroll
        for (int j = 0; j < 8; j++)
            o[j] = (short)f2b(src[(size_t)(kbase + j) * K + n]);
        *(bf16x8*)&dst[(size_t)ro * 8] = o;
    }
}

// ---------------------------------------------------------------------------
// Kernel 4 (VERBATIM, passed): fused wo GEMM + residual + LN1 + FFN + LN2.
// ---------------------------------------------------------------------------
__global__ __launch_bounds__(1024) void wo_ffn_ln(
        const unsigned short* __restrict__ AP,       // fragment-packed attn out
        const unsigned short* __restrict__ WoP,      // fragment-packed bf16
        const float* __restrict__ x,
        const float* __restrict__ gamma1,
        const unsigned short* __restrict__ W1P,      // fragment-packed bf16
        const unsigned short* __restrict__ W2P,      // fragment-packed bf16
        const float* __restrict__ gamma2,
        float* __restrict__ out) {
    __shared__ __align__(16) float Cp[2][16][264];         // wo partial C (34KB)
    __shared__ __align__(16) unsigned short xsb[16][264];  // ln1 (bf16)
    __shared__ __align__(16) unsigned short hsb[16][520];  // relu(h) (bf16)
    __shared__ __align__(16) float Cs[16][264];            // ffn C (fp32)
    __shared__ float ps1[16][16], ps2[16][16];
    __shared__ float mu[16], rsd[16];

    const int t      = threadIdx.x;          // 0..1023
    const int wave   = t >> 6;               // 0..15
    const int kslice = wave >> 3;            // 0..1  (wo phase, K=1024 each)
    const int wn     = wave & 7;             // col group n0 = wn*32
    const int lane   = t & 63;
    const int quad   = lane >> 4;
    const int c16    = lane & 15;
    const int r0     = blockIdx.x * 16;
    const f32x4 zero = (f32x4){0.f, 0.f, 0.f, 0.f};

    // ======== Phase 1: wo GEMM (K split x2), residual, LN1 -> xsb ========
    {
        const unsigned short* afrag = AP + ((size_t)blockIdx.x * 64 + kslice * 32) * 512
                                         + (size_t)lane * 8;
        const unsigned short* bfrag = WoP + (size_t)(wn * 2) * 32768
                                          + (size_t)(kslice * 32) * 512
                                          + (size_t)lane * 8;

        f32x4 acc[2];
        acc[0] = zero; acc[1] = zero;

        bf16x8 aa  = *(const bf16x8*)(afrag);
        bf16x8 bb0 = *(const bf16x8*)(bfrag);
        bf16x8 bb1 = *(const bf16x8*)(bfrag + 32768);

        for (int kc = 0; kc < 32; kc++) {
            const int kn = (kc + 1 < 32) ? kc + 1 : kc;     // last: dummy
            bf16x8 na  = *(const bf16x8*)(afrag + kn * 512);
            bf16x8 nb0 = *(const bf16x8*)(bfrag + kn * 512);
            bf16x8 nb1 = *(const bf16x8*)(bfrag + 32768 + kn * 512);

            acc[0] = __builtin_amdgcn_mfma_f32_16x16x32_bf16(aa, bb0, acc[0], 0, 0, 0);
            acc[1] = __builtin_amdgcn_mfma_f32_16x16x32_bf16(aa, bb1, acc[1], 0, 0, 0);

            aa = na; bb0 = nb0; bb1 = nb1;
        }

#pragma unroll
        for (int reg = 0; reg < 4; reg++) {
            const int row = quad * 4 + reg;
#pragma unroll
            for (int nt = 0; nt < 2; nt++)
                Cp[kslice][row][wn * 32 + nt * 16 + c16] = acc[nt][reg];
        }
    }
    __syncthreads();

    // reduce 2 k-slices + residual -> Cp[0]
#pragma unroll
    for (int p = 0; p < 4; p++) {
        const int idx = t + p * 1024;
        const int row = idx >> 8, col = idx & 255;
        float v = Cp[0][row][col] + Cp[1][row][col]
                + x[(size_t)(r0 + row) * 256 + col];
        Cp[0][row][col] = v;
    }
    __syncthreads();

    // LN1 stats
    if (t < 256) {
        const int row = t >> 4, seg = t & 15;
        float s = 0.f, s2 = 0.f;
#pragma unroll
        for (int j = 0; j < 16; j++) { float v = Cp[0][row][seg * 16 + j]; s += v; s2 += v * v; }
        ps1[row][seg] = s; ps2[row][seg] = s2;
    }
    __syncthreads();
    if (t < 16) {
        float s = 0.f, s2 = 0.f;
#pragma unroll
        for (int j = 0; j < 16; j++) { s += ps1[t][j]; s2 += ps2[t][j]; }
        float m = s * (1.0f / 256.0f);
        float var = s2 * (1.0f / 256.0f) - m * m;
        mu[t] = m; rsd[t] = rsqrtf(var + EPS);
    }
    __syncthreads();

    // LN1 -> xsb (bf16)
    {
        const int row = t >> 6;
        const int c4  = (t & 63) * 4;
        float4 cv = *(const float4*)&Cp[0][row][c4];
        float4 g4 = *(const float4*)&gamma1[c4];
        const float m = mu[row], rd = rsd[row];
        bf16x4 o4;
        o4[0] = (short)f2b((cv.x - m) * rd * g4.x);
        o4[1] = (short)f2b((cv.y - m) * rd * g4.y);
        o4[2] = (short)f2b((cv.z - m) * rd * g4.z);
        o4[3] = (short)f2b((cv.w - m) * rd * g4.w);
        *(bf16x4*)&xsb[row][c4] = o4;
    }

    // ======== Phase 2: FFN GEMM1 -> hsb ========
    const int w = wave;
    f32x4 acc1[2];
    acc1[0] = zero; acc1[1] = zero;
    const unsigned short* b1frag = W1P + (size_t)(w * 2) * 4096 + (size_t)lane * 8;
    bf16x8 b10 = *(const bf16x8*)(b1frag);
    bf16x8 b11 = *(const bf16x8*)(b1frag + 4096);
    __syncthreads();   // xsb visible

#pragma unroll
    for (int ks = 0; ks < 8; ks++) {
        const int ksn = (ks + 1 < 8) ? ks + 1 : ks;
        bf16x8 n0 = *(const bf16x8*)(b1frag + ksn * 512);
        bf16x8 n1 = *(const bf16x8*)(b1frag + 4096 + ksn * 512);
        bf16x8 af = *(const bf16x8*)&xsb[c16][ks * 32 + quad * 8];
        acc1[0] = __builtin_amdgcn_mfma_f32_16x16x32_bf16(af, b10, acc1[0], 0, 0, 0);
        acc1[1] = __builtin_amdgcn_mfma_f32_16x16x32_bf16(af, b11, acc1[1], 0, 0, 0);
        b10 = n0; b11 = n1;
    }

#pragma unroll
    for (int nt = 0; nt < 2; nt++)
#pragma unroll
        for (int reg = 0; reg < 4; reg++)
            hsb[quad * 4 + reg][w * 32 + nt * 16 + c16] =
                f2b(fmaxf(acc1[nt][reg], 0.f));
    __syncthreads();

    // ======== Phase 3: FFN GEMM2 -> Cs ========
    f32x4 acc2 = zero;
    const unsigned short* b2frag = W2P + (size_t)w * 8192 + (size_t)lane * 8;
    bf16x8 b20 = *(const bf16x8*)(b2frag);
#pragma unroll
    for (int ks = 0; ks < 16; ks++) {
        const int ksn = (ks + 1 < 16) ? ks + 1 : ks;
        bf16x8 n0 = *(const bf16x8*)(b2frag + ksn * 512);
        bf16x8 af = *(const bf16x8*)&hsb[c16][ks * 32 + quad * 8];
        acc2 = __builtin_amdgcn_mfma_f32_16x16x32_bf16(af, b20, acc2, 0, 0, 0);
        b20 = n0;
    }
#pragma unroll
    for (int reg = 0; reg < 4; reg++)
        Cs[quad * 4 + reg][w * 16 + c16] = acc2[reg];
    __syncthreads();

    // ======== Phase 4: LN2 -> out ========
    if (t < 256) {
        const int row = t >> 4, seg = t & 15;
        float s = 0.f, s2 = 0.f;
#pragma unroll
        for (int j = 0; j < 16; j++) { float v = Cs[row][seg * 16 + j]; s += v; s2 += v * v; }
        ps1[row][seg] = s; ps2[row][seg] = s2;
    }
    __syncthreads();
    if (t < 16) {
        float s = 0.f, s2 = 0.f;
#pragma unroll
        for (int j = 0; j < 16; j++) { s += ps1[t][j]; s2 += ps2[t][j]; }
        float m = s * (1.0f / DIM);
        float var = s2 * (1.0f / DIM) - m * m;
        mu[t] = m;
        rsd[t] = rsqrtf(var + EPS);
    }
    __syncthreads();

    {
        const int row = t >> 6, c4 = (t & 63) * 4;
        float4 cv = *(const float4*)&Cs[row][c4];
        float4 g4 = *(const float4*)&gamma2[c4];
        const float m = mu[row], rd = rsd[row];
        float4 o;
        o.x = (cv.x - m) * rd * g4.x;
        o.y = (cv.y - m) * rd * g4.y;
        o.z = (cv.z - m) * rd * g4.z;
        o.w = (cv.w - m) * rd * g4.w;
        *(float4*)&out[(size_t)(r0 + row) * DIM + c4] = o;
    }
}

// ---------------------------------------------------------------------------
extern "C" void kernel_launch(void* const* d_in, const int* in_sizes, int n_in,
                              void* d_out, int out_size, void* d_ws, size_t ws_size,
                              hipStream_t stream) {
    const float* x      = (const float*)d_in[0];
    const float* Wq     = (const float*)d_in[1];
    const float* Wk     = (const float*)d_in[2];
    const float* Wv     = (const float*)d_in[3];
    const float* Wo     = (const float*)d_in[4];
    const float* Wf1    = (const float*)d_in[5];
    const float* Wf2    = (const float*)d_in[6];
    const float* gamma1 = (const float*)d_in[7];
    const float* gamma2 = (const float*)d_in[8];
    float* out = (float*)d_out;

    // workspace layout unchanged.
    char* base = (char*)d_ws;
    unsigned short* qb      = (unsigned short*)(base);              // 2 MB
    unsigned short* kb      = (unsigned short*)(base +  2097152);   // 2 MB
    unsigned short* VP      = (unsigned short*)(base +  4194304);   // 2 MB
    unsigned short* AP      = (unsigned short*)(base +  6291456);   // 16 MB
    unsigned short* W1P     = (unsigned short*)(base + 41943040);   // 256 KB
    unsigned short* W2P     = (unsigned short*)(base + 42205184);   // 256 KB
    unsigned short* WoP     = (unsigned short*)(base + 44040192);   // 1 MB
    unsigned short* WqP     = (unsigned short*)(base + 45088768);   // 128 KB
    unsigned short* WkP     = (unsigned short*)(base + 45219840);   // 128 KB
    unsigned short* WvP     = (unsigned short*)(base + 45350912);   // 128 KB

    wprep<<<512, 256, 0, stream>>>(Wo, Wf1, Wf2, Wq, Wk, Wv,
                                   WoP, W1P, W2P, WqP, WkP, WvP);
    qkv_mfma<<<NROWS / 16, 1024, 0, stream>>>(x, WqP, WkP, WvP, qb, kb, VP);
    attn_mfma<<<256, 256, 0, stream>>>(qb, kb, VP, AP, 0);
    attn_mfma<<<256, 256, 0, stream>>>(qb, kb, VP, AP, 256);
    wo_ffn_ln<<<NROWS / 16, 1024, 0, stream>>>(AP, WoP, x, gamma1,
                                               W1P, W2P, gamma2, out);
}

// Round 19
// 148.753 us; speedup vs baseline: 1.1331x; 1.1331x over previous
//
#include <hip/hip_runtime.h>
#include <hip/hip_bf16.h>

#define DIM 256
#define HEADS 8
#define DHEAD 32
#define SEQ 2048
#define BATCH 2
#define NROWS (BATCH*SEQ)    // 4096 total rows
#define EPS 1e-5f

typedef __attribute__((ext_vector_type(8))) short bf16x8;   // MFMA A/B frag (4 VGPRs)
typedef __attribute__((ext_vector_type(4))) short bf16x4;   // 4 bf16 (8B)
typedef __attribute__((ext_vector_type(4))) float f32x4;    // MFMA C/D frag

__device__ __forceinline__ unsigned short f2b(float f) {
    __hip_bfloat16 h = __float2bfloat16(f);
    return *reinterpret_cast<unsigned short*>(&h);
}

// ---------------------------------------------------------------------------
// Kernel 1 (VERBATIM, passed): MFMA qkv projection; V written fragment-packed.
// ---------------------------------------------------------------------------
__global__ __launch_bounds__(1024) void qkv_mfma(
        const float* __restrict__ x,
        const unsigned short* __restrict__ WqP,
        const unsigned short* __restrict__ WkP,
        const unsigned short* __restrict__ WvP,
        unsigned short* __restrict__ qo,
        unsigned short* __restrict__ ko,
        unsigned short* __restrict__ VP) {
    __shared__ __align__(16) unsigned short xsb[16][264];

    const int t    = threadIdx.x;         // 0..1023
    const int w    = t >> 6;              // wave 0..15 = n-tile
    const int lane = t & 63;
    const int quad = lane >> 4;
    const int c16  = lane & 15;
    const int r0   = blockIdx.x * 16;
    const f32x4 zero = (f32x4){0.f, 0.f, 0.f, 0.f};

    // stage A: 16 rows x 256 cols fp32 -> bf16 LDS (1024 x float4)
    {
        const int row = t >> 6, c4 = (t & 63) * 4;
        float4 v4 = *(const float4*)&x[(size_t)(r0 + row) * 256 + c4];
        bf16x4 b4;
        b4[0] = (short)f2b(v4.x); b4[1] = (short)f2b(v4.y);
        b4[2] = (short)f2b(v4.z); b4[3] = (short)f2b(v4.w);
        *(bf16x4*)&xsb[row][c4] = b4;
    }

    f32x4 aq = zero, ak = zero, av = zero;
    const unsigned short* bq = WqP + (size_t)w * 4096 + (size_t)lane * 8;
    const unsigned short* bk = WkP + (size_t)w * 4096 + (size_t)lane * 8;
    const unsigned short* bv = WvP + (size_t)w * 4096 + (size_t)lane * 8;

    bf16x8 q0 = *(const bf16x8*)(bq);
    bf16x8 k0 = *(const bf16x8*)(bk);
    bf16x8 v0 = *(const bf16x8*)(bv);
    __syncthreads();   // xsb visible

#pragma unroll
    for (int ks = 0; ks < 8; ks++) {
        const int ksn = (ks + 1 < 8) ? ks + 1 : ks;     // last iter: dummy
        bf16x8 qn = *(const bf16x8*)(bq + ksn * 512);
        bf16x8 kn = *(const bf16x8*)(bk + ksn * 512);
        bf16x8 vn = *(const bf16x8*)(bv + ksn * 512);
        bf16x8 af = *(const bf16x8*)&xsb[c16][ks * 32 + quad * 8];
        aq = __builtin_amdgcn_mfma_f32_16x16x32_bf16(af, q0, aq, 0, 0, 0);
        ak = __builtin_amdgcn_mfma_f32_16x16x32_bf16(af, k0, ak, 0, 0, 0);
        av = __builtin_amdgcn_mfma_f32_16x16x32_bf16(af, v0, av, 0, 0, 0);
        q0 = qn; k0 = kn; v0 = vn;
    }

    // epilogue (C/D layout: row=quad*4+reg, col=w*16+c16)
    const float scale = 0.17677669529663687f;  // 1/sqrt(32)
    const int col = w * 16 + c16;
#pragma unroll
    for (int reg = 0; reg < 4; reg++) {
        const int row = r0 + quad * 4 + reg;
        qo[(size_t)row * 256 + col] = f2b(aq[reg] * scale);
        ko[(size_t)row * 256 + col] = f2b(ak[reg]);
    }
    {   // V fragment-packed
        const int bb   = r0 >> 11;
        const int key  = (r0 & 2047) + quad * 4;          // first of 4 keys
        const int jt   = key >> 6;
        const int kh   = (key >> 5) & 1;
        const int qv   = (key >> 3) & 3;
        const int j0   = key & 7;                          // 0 or 4
        const size_t off = ((((size_t)(bb * 32 + jt) * 32) + (w * 2 + kh)) * 64
                            + qv * 16 + c16) * 8 + j0;
        bf16x4 v4;
        v4[0] = (short)f2b(av[0]); v4[1] = (short)f2b(av[1]);
        v4[2] = (short)f2b(av[2]); v4[3] = (short)f2b(av[3]);
        *(bf16x4*)&VP[off] = v4;
    }
}

// ---------------------------------------------------------------------------
// Kernel 2 (REVERTED to single 512-block launch + wprep-fold this round):
//  - blocks 0..511: flash attention (round-14 structure, AP output) — the
//    2-blocks/CU co-residency the split destroyed is restored.
//  - blocks 512..895: Wo/W1/W2 fragment packing (1 row/thread), hidden in
//    attn's latency shadow; wo_ffn (next launch) waits on the whole grid,
//    giving producer->consumer ordering for free.
// ---------------------------------------------------------------------------
__global__ __launch_bounds__(256, 2) void attn_mfma(
        const unsigned short* __restrict__ qb,
        const unsigned short* __restrict__ kb,
        const unsigned short* __restrict__ VP,
        unsigned short* __restrict__ AP,
        const float* __restrict__ Wo,
        const float* __restrict__ Wf1,
        const float* __restrict__ Wf2,
        unsigned short* __restrict__ WoP,
        unsigned short* __restrict__ W1P,
        unsigned short* __restrict__ W2P) {
    __shared__ __align__(16) unsigned short Ks[2][128][40];  // 20.5 KB
    __shared__ __align__(16) unsigned short Ps[2][64][132];  // 33.8 KB
    __shared__ float linv[64];

    if (blockIdx.x >= 512) {
        // ---- weight-packing blocks: 98304 rows, 1 row/thread ----
        const int r = (blockIdx.x - 512) * 256 + threadIdx.x;
        const float* src;
        unsigned short* dst;
        int ro, K;
        int n, kbase;
        if (r < 65536) {
            ro = r;
            int l = ro & 63, KS = (ro >> 6) & 63, NT = ro >> 12;
            n = NT * 16 + (l & 15); kbase = KS * 32 + ((l >> 4) << 3);
            src = Wo; dst = WoP; K = 256;
        } else if (r < 81920) {
            ro = r - 65536;
            int l = ro & 63, KS = (ro >> 6) & 7, NT = ro >> 9;
            n = NT * 16 + (l & 15); kbase = KS * 32 + ((l >> 4) << 3);
            src = Wf1; dst = W1P; K = 512;
        } else {
            ro = r - 81920;
            int l = ro & 63, KS = (ro >> 6) & 15, NT = ro >> 10;
            n = NT * 16 + (l & 15); kbase = KS * 32 + ((l >> 4) << 3);
            src = Wf2; dst = W2P; K = 256;
        }
        bf16x8 o;
#pragma unroll
        for (int j = 0; j < 8; j++)
            o[j] = (short)f2b(src[(size_t)(kbase + j) * K + n]);
        *(bf16x8*)&dst[(size_t)ro * 8] = o;
        return;
    }

    const int t    = threadIdx.x;
    const int w    = t >> 6;
    const int lane = t & 63;
    const int quad = lane >> 4;
    const int c16  = lane & 15;

    const int fid  = blockIdx.x;
    const int h    = fid & 7;
    const int b    = (fid >> 3) & 1;
    const int i0b  = (fid >> 4) * 64;        // block q-row base
    const int i0   = i0b + w * 16;           // this wave's q rows (QK phase)

    const size_t qk_head = ((size_t)b * SEQ) * DIM + h * DHEAD;
    const int ncol0 = w * 64;                // this wave's PV column slice

    bf16x8 qf = *(const bf16x8*)&qb[qk_head + (size_t)(i0 + c16) * DIM + quad * 8];

    const int kkey  = t >> 2, kpart = t & 3;   // 2 K-frags/thread (128 keys)
    const unsigned short* ksrc = kb + qk_head + (size_t)kkey * DIM + kpart * 8;

    f32x4 acc[4][4];
#pragma unroll
    for (int rt = 0; rt < 4; rt++)
#pragma unroll
        for (int ct = 0; ct < 4; ct++) acc[rt][ct] = (f32x4){0.f, 0.f, 0.f, 0.f};
    float lrow[4] = {0.f, 0.f, 0.f, 0.f};
    const f32x4 zero = (f32x4){0.f, 0.f, 0.f, 0.f};

    bf16x8 kregA = *(const bf16x8*)(ksrc);                      // keys kkey
    bf16x8 kregB = *(const bf16x8*)(ksrc + (size_t)64 * DIM);   // keys 64+kkey

    for (int jt = 0; jt < SEQ / 128; jt++) {
        const int cur = jt & 1;
        // commit K tile jt (prefetched) -> LDS buffer cur
        *(bf16x8*)&Ks[cur][kkey][kpart * 8]      = kregA;
        *(bf16x8*)&Ks[cur][64 + kkey][kpart * 8] = kregB;
        __syncthreads();   // (B) K tile jt visible

        // V fragments for this 128-key tile: 16 coalesced 1KB loads
        bf16x8 vreg[16];
#pragma unroll
        for (int hh = 0; hh < 2; hh++) {
            const unsigned short* vsrc = VP +
                (((size_t)(b * 32 + jt * 2 + hh) * 32) + w * 8) * 512 + (size_t)lane * 8;
#pragma unroll
            for (int ct = 0; ct < 4; ct++) {
                vreg[(hh * 2 + 0) * 4 + ct] = *(const bf16x8*)(vsrc + (ct * 2 + 0) * 512);
                vreg[(hh * 2 + 1) * 4 + ct] = *(const bf16x8*)(vsrc + (ct * 2 + 1) * 512);
            }
        }

        // K prefetch for jt+1 (retires under compute)
        if (jt + 1 < SEQ / 128) {
            const size_t j1 = (size_t)((jt + 1) * 128) * DIM;
            kregA = *(const bf16x8*)(ksrc + j1);
            kregB = *(const bf16x8*)(ksrc + j1 + (size_t)64 * DIM);
        }

        // ---- QK^T (M-split): this wave's 16 rows vs 128 keys, K from LDS
        f32x4 s[8];
#pragma unroll
        for (int kt = 0; kt < 8; kt++) {
            bf16x8 kf = *(const bf16x8*)&Ks[cur][kt * 16 + c16][quad * 8];
            s[kt] = __builtin_amdgcn_mfma_f32_16x16x32_bf16(qf, kf, zero, 0, 0, 0);
        }

        // ---- softmax (no max subtraction), stash P into buffer cur
#pragma unroll
        for (int kt = 0; kt < 8; kt++) {
#pragma unroll
            for (int reg = 0; reg < 4; reg++) {
                float p = __expf(s[kt][reg]);
                lrow[reg] += p;
                Ps[cur][w * 16 + quad * 4 + reg][kt * 16 + c16] = f2b(p);
            }
        }
        __syncthreads();   // (C) P visible to all waves

        // ---- PV (N-split): all 64 rows x this wave's 64 cols, V from regs
#pragma unroll
        for (int kh = 0; kh < 4; kh++) {
#pragma unroll
            for (int rt = 0; rt < 4; rt++) {
                bf16x8 af = *(const bf16x8*)&Ps[cur][rt * 16 + c16][kh * 32 + quad * 8];
#pragma unroll
                for (int ct = 0; ct < 4; ct++)
                    acc[rt][ct] = __builtin_amdgcn_mfma_f32_16x16x32_bf16(
                        af, vreg[kh * 4 + ct], acc[rt][ct], 0, 0, 0);
            }
        }
        // no (A) barrier: next iteration writes the other buffer
    }

    // ---- l broadcast: owner wave writes 1/l for its 16 rows
#pragma unroll
    for (int reg = 0; reg < 4; reg++) {
        float l = lrow[reg];
#pragma unroll
        for (int m = 1; m <= 8; m <<= 1) l += __shfl_xor(l, m, 64);
        if (c16 == 0) linv[w * 16 + quad * 4 + reg] = 1.f / l;
    }
    __syncthreads();

    // ---- write out fragment-packed (AP)
    const int R16base = (b * SEQ + i0b) >> 4;   // b*128 + i0b/16
#pragma unroll
    for (int rt = 0; rt < 4; rt++) {
#pragma unroll
        for (int reg = 0; reg < 4; reg++) {
            const float inv = linv[rt * 16 + quad * 4 + reg];
#pragma unroll
            for (int ct = 0; ct < 4; ct++) {
                const size_t frag = (size_t)(R16base + rt) * 64
                                  + h * 8 + w * 2 + (ct >> 1);
                const int l2 = ((ct * 2 + (c16 >> 3)) & 3) * 16 + quad * 4 + reg;
                AP[frag * 512 + l2 * 8 + (c16 & 7)] = f2b(acc[rt][ct][reg] * inv);
            }
        }
    }
}

// ---------------------------------------------------------------------------
// Kernel 3 (SHRUNK this round): q/k/v weight packing only (24576 rows).
//  Wo/W1/W2 packing moved into the attn launch (blocks 512..895).
// ---------------------------------------------------------------------------
__global__ void wprep_qkv(const float* __restrict__ Wq,
                          const float* __restrict__ Wk,
                          const float* __restrict__ Wv,
                          unsigned short* __restrict__ WqP,
                          unsigned short* __restrict__ WkP,
                          unsigned short* __restrict__ WvP) {
    const int r = blockIdx.x * 256 + threadIdx.x;   // 0..24575
    if (r >= 24576) return;
    const int ro = r & 8191;
    const int l = ro & 63, KS = (ro >> 6) & 7, NT = ro >> 9;
    const int n = NT * 16 + (l & 15);
    const int kbase = KS * 32 + ((l >> 4) << 3);
    const float* src = (r < 8192) ? Wq : (r < 16384) ? Wk : Wv;
    unsigned short* dst = (r < 8192) ? WqP : (r < 16384) ? WkP : WvP;
    bf16x8 o;
#pragma unroll
    for (int j = 0; j < 8; j++)
        o[j] = (short)f2b(src[(size_t)(kbase + j) * 256 + n]);
    *(bf16x8*)&dst[(size_t)ro * 8] = o;
}

// ---------------------------------------------------------------------------
// Kernel 4 (VERBATIM, passed): fused wo GEMM + residual + LN1 + FFN + LN2.
// ---------------------------------------------------------------------------
__global__ __launch_bounds__(1024) void wo_ffn_ln(
        const unsigned short* __restrict__ AP,       // fragment-packed attn out
        const unsigned short* __restrict__ WoP,      // fragment-packed bf16
        const float* __restrict__ x,
        const float* __restrict__ gamma1,
        const unsigned short* __restrict__ W1P,      // fragment-packed bf16
        const unsigned short* __restrict__ W2P,      // fragment-packed bf16
        const float* __restrict__ gamma2,
        float* __restrict__ out) {
    __shared__ __align__(16) float Cp[2][16][264];         // wo partial C (34KB)
    __shared__ __align__(16) unsigned short xsb[16][264];  // ln1 (bf16)
    __shared__ __align__(16) unsigned short hsb[16][520];  // relu(h) (bf16)
    __shared__ __align__(16) float Cs[16][264];            // ffn C (fp32)
    __shared__ float ps1[16][16], ps2[16][16];
    __shared__ float mu[16], rsd[16];

    const int t      = threadIdx.x;          // 0..1023
    const int wave   = t >> 6;               // 0..15
    const int kslice = wave >> 3;            // 0..1  (wo phase, K=1024 each)
    const int wn     = wave & 7;             // col group n0 = wn*32
    const int lane   = t & 63;
    const int quad   = lane >> 4;
    const int c16    = lane & 15;
    const int r0     = blockIdx.x * 16;
    const f32x4 zero = (f32x4){0.f, 0.f, 0.f, 0.f};

    // ======== Phase 1: wo GEMM (K split x2), residual, LN1 -> xsb ========
    {
        const unsigned short* afrag = AP + ((size_t)blockIdx.x * 64 + kslice * 32) * 512
                                         + (size_t)lane * 8;
        const unsigned short* bfrag = WoP + (size_t)(wn * 2) * 32768
                                          + (size_t)(kslice * 32) * 512
                                          + (size_t)lane * 8;

        f32x4 acc[2];
        acc[0] = zero; acc[1] = zero;

        bf16x8 aa  = *(const bf16x8*)(afrag);
        bf16x8 bb0 = *(const bf16x8*)(bfrag);
        bf16x8 bb1 = *(const bf16x8*)(bfrag + 32768);

        for (int kc = 0; kc < 32; kc++) {
            const int kn = (kc + 1 < 32) ? kc + 1 : kc;     // last: dummy
            bf16x8 na  = *(const bf16x8*)(afrag + kn * 512);
            bf16x8 nb0 = *(const bf16x8*)(bfrag + kn * 512);
            bf16x8 nb1 = *(const bf16x8*)(bfrag + 32768 + kn * 512);

            acc[0] = __builtin_amdgcn_mfma_f32_16x16x32_bf16(aa, bb0, acc[0], 0, 0, 0);
            acc[1] = __builtin_amdgcn_mfma_f32_16x16x32_bf16(aa, bb1, acc[1], 0, 0, 0);

            aa = na; bb0 = nb0; bb1 = nb1;
        }

#pragma unroll
        for (int reg = 0; reg < 4; reg++) {
            const int row = quad * 4 + reg;
#pragma unroll
            for (int nt = 0; nt < 2; nt++)
                Cp[kslice][row][wn * 32 + nt * 16 + c16] = acc[nt][reg];
        }
    }
    __syncthreads();

    // reduce 2 k-slices + residual -> Cp[0]
#pragma unroll
    for (int p = 0; p < 4; p++) {
        const int idx = t + p * 1024;
        const int row = idx >> 8, col = idx & 255;
        float v = Cp[0][row][col] + Cp[1][row][col]
                + x[(size_t)(r0 + row) * 256 + col];
        Cp[0][row][col] = v;
    }
    __syncthreads();

    // LN1 stats
    if (t < 256) {
        const int row = t >> 4, seg = t & 15;
        float s = 0.f, s2 = 0.f;
#pragma unroll
        for (int j = 0; j < 16; j++) { float v = Cp[0][row][seg * 16 + j]; s += v; s2 += v * v; }
        ps1[row][seg] = s; ps2[row][seg] = s2;
    }
    __syncthreads();
    if (t < 16) {
        float s = 0.f, s2 = 0.f;
#pragma unroll
        for (int j = 0; j < 16; j++) { s += ps1[t][j]; s2 += ps2[t][j]; }
        float m = s * (1.0f / 256.0f);
        float var = s2 * (1.0f / 256.0f) - m * m;
        mu[t] = m; rsd[t] = rsqrtf(var + EPS);
    }
    __syncthreads();

    // LN1 -> xsb (bf16)
    {
        const int row = t >> 6;
        const int c4  = (t & 63) * 4;
        float4 cv = *(const float4*)&Cp[0][row][c4];
        float4 g4 = *(const float4*)&gamma1[c4];
        const float m = mu[row], rd = rsd[row];
        bf16x4 o4;
        o4[0] = (short)f2b((cv.x - m) * rd * g4.x);
        o4[1] = (short)f2b((cv.y - m) * rd * g4.y);
        o4[2] = (short)f2b((cv.z - m) * rd * g4.z);
        o4[3] = (short)f2b((cv.w - m) * rd * g4.w);
        *(bf16x4*)&xsb[row][c4] = o4;
    }

    // ======== Phase 2: FFN GEMM1 -> hsb ========
    const int w = wave;
    f32x4 acc1[2];
    acc1[0] = zero; acc1[1] = zero;
    const unsigned short* b1frag = W1P + (size_t)(w * 2) * 4096 + (size_t)lane * 8;
    bf16x8 b10 = *(const bf16x8*)(b1frag);
    bf16x8 b11 = *(const bf16x8*)(b1frag + 4096);
    __syncthreads();   // xsb visible

#pragma unroll
    for (int ks = 0; ks < 8; ks++) {
        const int ksn = (ks + 1 < 8) ? ks + 1 : ks;
        bf16x8 n0 = *(const bf16x8*)(b1frag + ksn * 512);
        bf16x8 n1 = *(const bf16x8*)(b1frag + 4096 + ksn * 512);
        bf16x8 af = *(const bf16x8*)&xsb[c16][ks * 32 + quad * 8];
        acc1[0] = __builtin_amdgcn_mfma_f32_16x16x32_bf16(af, b10, acc1[0], 0, 0, 0);
        acc1[1] = __builtin_amdgcn_mfma_f32_16x16x32_bf16(af, b11, acc1[1], 0, 0, 0);
        b10 = n0; b11 = n1;
    }

#pragma unroll
    for (int nt = 0; nt < 2; nt++)
#pragma unroll
        for (int reg = 0; reg < 4; reg++)
            hsb[quad * 4 + reg][w * 32 + nt * 16 + c16] =
                f2b(fmaxf(acc1[nt][reg], 0.f));
    __syncthreads();

    // ======== Phase 3: FFN GEMM2 -> Cs ========
    f32x4 acc2 = zero;
    const unsigned short* b2frag = W2P + (size_t)w * 8192 + (size_t)lane * 8;
    bf16x8 b20 = *(const bf16x8*)(b2frag);
#pragma unroll
    for (int ks = 0; ks < 16; ks++) {
        const int ksn = (ks + 1 < 16) ? ks + 1 : ks;
        bf16x8 n0 = *(const bf16x8*)(b2frag + ksn * 512);
        bf16x8 af = *(const bf16x8*)&hsb[c16][ks * 32 + quad * 8];
        acc2 = __builtin_amdgcn_mfma_f32_16x16x32_bf16(af, b20, acc2, 0, 0, 0);
        b20 = n0;
    }
#pragma unroll
    for (int reg = 0; reg < 4; reg++)
        Cs[quad * 4 + reg][w * 16 + c16] = acc2[reg];
    __syncthreads();

    // ======== Phase 4: LN2 -> out ========
    if (t < 256) {
        const int row = t >> 4, seg = t & 15;
        float s = 0.f, s2 = 0.f;
#pragma unroll
        for (int j = 0; j < 16; j++) { float v = Cs[row][seg * 16 + j]; s += v; s2 += v * v; }
        ps1[row][seg] = s; ps2[row][seg] = s2;
    }
    __syncthreads();
    if (t < 16) {
        float s = 0.f, s2 = 0.f;
#pragma unroll
        for (int j = 0; j < 16; j++) { s += ps1[t][j]; s2 += ps2[t][j]; }
        float m = s * (1.0f / DIM);
        float var = s2 * (1.0f / DIM) - m * m;
        mu[t] = m;
        rsd[t] = rsqrtf(var + EPS);
    }
    __syncthreads();

    {
        const int row = t >> 6, c4 = (t & 63) * 4;
        float4 cv = *(const float4*)&Cs[row][c4];
        float4 g4 = *(const float4*)&gamma2[c4];
        const float m = mu[row], rd = rsd[row];
        float4 o;
        o.x = (cv.x - m) * rd * g4.x;
        o.y = (cv.y - m) * rd * g4.y;
        o.z = (cv.z - m) * rd * g4.z;
        o.w = (cv.w - m) * rd * g4.w;
        *(float4*)&out[(size_t)(r0 + row) * DIM + c4] = o;
    }
}

// ---------------------------------------------------------------------------
extern "C" void kernel_launch(void* const* d_in, const int* in_sizes, int n_in,
                              void* d_out, int out_size, void* d_ws, size_t ws_size,
                              hipStream_t stream) {
    const float* x      = (const float*)d_in[0];
    const float* Wq     = (const float*)d_in[1];
    const float* Wk     = (const float*)d_in[2];
    const float* Wv     = (const float*)d_in[3];
    const float* Wo     = (const float*)d_in[4];
    const float* Wf1    = (const float*)d_in[5];
    const float* Wf2    = (const float*)d_in[6];
    const float* gamma1 = (const float*)d_in[7];
    const float* gamma2 = (const float*)d_in[8];
    float* out = (float*)d_out;

    // workspace layout unchanged.
    char* base = (char*)d_ws;
    unsigned short* qb      = (unsigned short*)(base);              // 2 MB
    unsigned short* kb      = (unsigned short*)(base +  2097152);   // 2 MB
    unsigned short* VP      = (unsigned short*)(base +  4194304);   // 2 MB
    unsigned short* AP      = (unsigned short*)(base +  6291456);   // 16 MB
    unsigned short* W1P     = (unsigned short*)(base + 41943040);   // 256 KB
    unsigned short* W2P     = (unsigned short*)(base + 42205184);   // 256 KB
    unsigned short* WoP     = (unsigned short*)(base + 44040192);   // 1 MB
    unsigned short* WqP     = (unsigned short*)(base + 45088768);   // 128 KB
    unsigned short* WkP     = (unsigned short*)(base + 45219840);   // 128 KB
    unsigned short* WvP     = (unsigned short*)(base + 45350912);   // 128 KB

    wprep_qkv<<<96, 256, 0, stream>>>(Wq, Wk, Wv, WqP, WkP, WvP);
    qkv_mfma<<<NROWS / 16, 1024, 0, stream>>>(x, WqP, WkP, WvP, qb, kb, VP);
    attn_mfma<<<896, 256, 0, stream>>>(qb, kb, VP, AP,
                                       Wo, Wf1, Wf2, WoP, W1P, W2P);
    wo_ffn_ln<<<NROWS / 16, 1024, 0, stream>>>(AP, WoP, x, gamma1,
                                               W1P, W2P, gamma2, out);
}